// Round 1
// baseline (67.029 us; speedup 1.0000x reference)
//
#include <hip/hip_runtime.h>

// Problem constants (from reference): pred (B,C,S) f32, labels (B,S) int, scalar f32 out.
constexpr int   Bn   = 512;
constexpr int   Cn   = 4;
constexpr int   Sn   = 16384;
constexpr int   PADv = 3;
constexpr float Qv   = 0.7f;
constexpr int   BPB  = 8;             // blocks per batch in gce kernel
constexpr int   CHUNK = Sn / BPB;     // 2048 positions per block

// ---------------------------------------------------------------------------
// Kernel A: per batch, find j = first index where label == PAD (else S-1).
// Chunked scan with early exit (first pad is ~0.75*S on average).
// Block 0 / thread 0 also zeroes d_out (harness poisons it between timings).
// ---------------------------------------------------------------------------
__global__ __launch_bounds__(256) void find_j_kernel(
    const int* __restrict__ labels, int* __restrict__ jarr, float* __restrict__ out)
{
    const int b = blockIdx.x;
    const int t = threadIdx.x;
    if (b == 0 && t == 0) out[0] = 0.0f;

    const int4* row = reinterpret_cast<const int4*>(labels + (size_t)b * Sn);

    __shared__ int found;
    if (t == 0) found = 0;
    __syncthreads();

    int best = 0x7fffffff;
    for (int base = 0; base < Sn; base += 1024) {   // 1024 labels / chunk
        const int4 v = row[(base >> 2) + t];
        const int  s = base + t * 4;
        if (v.x == PADv) best = min(best, s + 0);
        if (v.y == PADv) best = min(best, s + 1);
        if (v.z == PADv) best = min(best, s + 2);
        if (v.w == PADv) best = min(best, s + 3);
        if (best != 0x7fffffff) found = 1;
        __syncthreads();
        const int f = found;
        __syncthreads();                            // double barrier: consistent break
        if (f) break;
    }

    // block-wide min reduce: 64-lane shuffle then across the 4 waves via LDS
    #pragma unroll
    for (int off = 32; off > 0; off >>= 1)
        best = min(best, __shfl_down(best, off, 64));
    __shared__ int wmin[4];
    if ((t & 63) == 0) wmin[t >> 6] = best;
    __syncthreads();
    if (t == 0) {
        const int m = min(min(wmin[0], wmin[1]), min(wmin[2], wmin[3]));
        jarr[b] = (m == 0x7fffffff) ? (Sn - 1) : m;
    }
}

// ---------------------------------------------------------------------------
// Kernel B: fused softmax(3) -> p_true -> (1 - p^Q), masked sum over s < j,
// scaled by 1/(Q*j*B), atomically accumulated into the scalar output.
// ---------------------------------------------------------------------------
__device__ __forceinline__ float gce_elem(float l0, float l1, float l2, int lb, bool on)
{
    const float m   = fmaxf(fmaxf(l0, l1), l2);
    const float e0  = __expf(l0 - m);
    const float e1  = __expf(l1 - m);
    const float e2  = __expf(l2 - m);
    const float inv = 1.0f / (e0 + e1 + e2);
    lb = min(max(lb, 0), 2);                          // safe_lab = clip(labels,0,2)
    float pt = ((lb == 0) ? e0 : (lb == 1) ? e1 : e2) * inv;
    pt = fminf(fmaxf(pt, 1e-7f), 1.0f);               // clip(probs,1e-7,1)
    const float g = 1.0f - __powf(pt, Qv);
    return on ? g : 0.0f;
}

__global__ __launch_bounds__(256) void gce_kernel(
    const float* __restrict__ pred, const int* __restrict__ labels,
    const int* __restrict__ jarr, float* __restrict__ out)
{
    const int b   = blockIdx.x >> 3;          // / BPB
    const int blk = blockIdx.x & (BPB - 1);
    const int j   = jarr[b];
    const int s0  = blk * CHUNK;
    if (s0 >= j) return;                      // whole chunk is masked out
    const int send = min(s0 + CHUNK, j);

    const float4* p0  = reinterpret_cast<const float4*>(pred + ((size_t)b * Cn + 0) * Sn);
    const float4* p1  = reinterpret_cast<const float4*>(pred + ((size_t)b * Cn + 1) * Sn);
    const float4* p2  = reinterpret_cast<const float4*>(pred + ((size_t)b * Cn + 2) * Sn);
    const int4*   lab = reinterpret_cast<const int4*>(labels + (size_t)b * Sn);

    const int t = threadIdx.x;
    float acc = 0.0f;
    for (int s = s0 + t * 4; s < send; s += 1024) {   // 256 thr * 4 elems
        const int    vi = s >> 2;
        const float4 a  = p0[vi];
        const float4 c1 = p1[vi];
        const float4 c2 = p2[vi];
        const int4   lv = lab[vi];
        acc += gce_elem(a.x, c1.x, c2.x, lv.x, (s + 0) < send);
        acc += gce_elem(a.y, c1.y, c2.y, lv.y, (s + 1) < send);
        acc += gce_elem(a.z, c1.z, c2.z, lv.z, (s + 2) < send);
        acc += gce_elem(a.w, c1.w, c2.w, lv.w, (s + 3) < send);
    }

    // block-wide sum reduce
    #pragma unroll
    for (int off = 32; off > 0; off >>= 1)
        acc += __shfl_down(acc, off, 64);
    __shared__ float wsum[4];
    if ((t & 63) == 0) wsum[t >> 6] = acc;
    __syncthreads();
    if (t == 0) {
        const float total = wsum[0] + wsum[1] + wsum[2] + wsum[3];
        const float scale = 1.0f / (Qv * (float)j * (float)Bn);
        atomicAdd(out, total * scale);
    }
}

// ---------------------------------------------------------------------------
extern "C" void kernel_launch(void* const* d_in, const int* in_sizes, int n_in,
                              void* d_out, int out_size, void* d_ws, size_t ws_size,
                              hipStream_t stream)
{
    const float* pred   = (const float*)d_in[0];
    const int*   labels = (const int*)d_in[1];
    float*       out    = (float*)d_out;
    int*         jarr   = (int*)d_ws;        // 512 ints of scratch

    hipLaunchKernelGGL(find_j_kernel, dim3(Bn), dim3(256), 0, stream,
                       labels, jarr, out);
    hipLaunchKernelGGL(gce_kernel, dim3(Bn * BPB), dim3(256), 0, stream,
                       pred, labels, jarr, out);
}

// Round 2
// 27.920 us; speedup vs baseline: 2.4008x; 2.4008x over previous
//
#include <hip/hip_runtime.h>

// pred (B,C,S) f32, labels (B,S) int32, scalar f32 out.
constexpr int   Bn    = 512;
constexpr int   Cn    = 4;
constexpr int   Sn    = 16384;
constexpr int   PADv  = 3;
constexpr float Qv    = 0.7f;
constexpr int   BPB   = 8;            // blocks per batch
constexpr int   CHUNK = Sn / BPB;     // 2048 positions per block (exact tiling)

// ws layout: float psum[Bn*BPB]; int pcnt[Bn*BPB]; float lastg[Bn]
// Every slot is written unconditionally each call -> no init, no atomics,
// deterministic reduction order.

__device__ __forceinline__ float gce_raw(float l0, float l1, float l2, int lb)
{
    const float m   = fmaxf(fmaxf(l0, l1), l2);
    const float e0  = __expf(l0 - m);
    const float e1  = __expf(l1 - m);
    const float e2  = __expf(l2 - m);
    const float inv = 1.0f / (e0 + e1 + e2);
    const int   c   = min(max(lb, 0), 2);          // safe_lab
    float pt = ((c == 0) ? e0 : (c == 1) ? e1 : e2) * inv;
    pt = fminf(fmaxf(pt, 1e-7f), 1.0f);            // clip(probs)
    return 1.0f - __expf(Qv * __logf(pt));         // 1 - pt^Q   (pt >= 1e-7 > 0)
}

// ---------------------------------------------------------------------------
// Main pass: per block (b, blk), stream CHUNK positions. mask = (label != PAD)
// (PAD is a contiguous suffix, so this equals s < j and count(non-pad) = j).
// Skip the 3 pred-stream loads when the whole wave's span is pad.
// ---------------------------------------------------------------------------
__global__ __launch_bounds__(256) void gce_main(
    const float* __restrict__ pred, const int* __restrict__ labels,
    float* __restrict__ psum, int* __restrict__ pcnt, float* __restrict__ lastg)
{
    const int b   = blockIdx.x >> 3;          // / BPB
    const int blk = blockIdx.x & (BPB - 1);
    const int s0  = blk * CHUNK;
    const int t   = threadIdx.x;

    const float4* p0  = reinterpret_cast<const float4*>(pred + ((size_t)b * Cn + 0) * Sn);
    const float4* p1  = reinterpret_cast<const float4*>(pred + ((size_t)b * Cn + 1) * Sn);
    const float4* p2  = reinterpret_cast<const float4*>(pred + ((size_t)b * Cn + 2) * Sn);
    const int4*   lab = reinterpret_cast<const int4*>(labels + (size_t)b * Sn);

    float acc = 0.0f;
    int   cnt = 0;
    float gl  = 0.0f;   // unmasked gce at global last position (no-pad fallback)

    #pragma unroll
    for (int it = 0; it < CHUNK / 1024; ++it) {   // static trip count (2)
        const int  s  = s0 + it * 1024 + t * 4;
        const int  vi = s >> 2;
        const int4 lv = lab[vi];
        const bool allpad = (lv.x == PADv) & (lv.y == PADv) &
                            (lv.z == PADv) & (lv.w == PADv);
        if (!__all(allpad)) {                      // wave-uniform branch
            const float4 a  = p0[vi];
            const float4 c1 = p1[vi];
            const float4 c2 = p2[vi];
            const float g0 = gce_raw(a.x, c1.x, c2.x, lv.x);
            const float g1 = gce_raw(a.y, c1.y, c2.y, lv.y);
            const float g2 = gce_raw(a.z, c1.z, c2.z, lv.z);
            const float g3 = gce_raw(a.w, c1.w, c2.w, lv.w);
            if (lv.x != PADv) { acc += g0; ++cnt; }
            if (lv.y != PADv) { acc += g1; ++cnt; }
            if (lv.z != PADv) { acc += g2; ++cnt; }
            if (lv.w != PADv) { acc += g3; ++cnt; }
            if (s + 3 == Sn - 1) gl = g3;
        }
    }

    // block-wide reduce: 64-lane shuffle, then across 4 waves via LDS
    #pragma unroll
    for (int off = 32; off > 0; off >>= 1) {
        acc += __shfl_down(acc, off, 64);
        cnt += __shfl_down(cnt, off, 64);
    }
    __shared__ float wsum[4];
    __shared__ int   wcnt[4];
    if ((t & 63) == 0) { wsum[t >> 6] = acc; wcnt[t >> 6] = cnt; }
    __syncthreads();
    if (t == 0) {
        psum[blockIdx.x] = wsum[0] + wsum[1] + wsum[2] + wsum[3];
        pcnt[blockIdx.x] = wcnt[0] + wcnt[1] + wcnt[2] + wcnt[3];
    }
    if (blk == BPB - 1 && t == 255) lastg[b] = gl;  // owner of s = Sn-1
}

// ---------------------------------------------------------------------------
// Finisher: one block combines the 4096 partials -> scalar mean.
// ---------------------------------------------------------------------------
__global__ __launch_bounds__(256) void gce_final(
    const float* __restrict__ psum, const int* __restrict__ pcnt,
    const float* __restrict__ lastg, float* __restrict__ out)
{
    const int t = threadIdx.x;
    float acc = 0.0f;
    for (int b = t; b < Bn; b += 256) {
        float s = 0.0f; int c = 0;
        #pragma unroll
        for (int k = 0; k < BPB; ++k) {
            s += psum[b * BPB + k];
            c += pcnt[b * BPB + k];
        }
        float jf;
        if (c == Sn) { s -= lastg[b]; jf = (float)(Sn - 1); }  // no-pad corner
        else         { jf = (float)c; }
        acc += s / (Qv * jf);
    }
    #pragma unroll
    for (int off = 32; off > 0; off >>= 1) acc += __shfl_down(acc, off, 64);
    __shared__ float w[4];
    if ((t & 63) == 0) w[t >> 6] = acc;
    __syncthreads();
    if (t == 0) out[0] = (w[0] + w[1] + w[2] + w[3]) / (float)Bn;
}

// ---------------------------------------------------------------------------
extern "C" void kernel_launch(void* const* d_in, const int* in_sizes, int n_in,
                              void* d_out, int out_size, void* d_ws, size_t ws_size,
                              hipStream_t stream)
{
    const float* pred   = (const float*)d_in[0];
    const int*   labels = (const int*)d_in[1];
    float*       out    = (float*)d_out;

    float* psum  = (float*)d_ws;                 // 4096 f32
    int*   pcnt  = (int*)(psum + Bn * BPB);      // 4096 i32
    float* lastg = (float*)(pcnt + Bn * BPB);    // 512 f32

    hipLaunchKernelGGL(gce_main, dim3(Bn * BPB), dim3(256), 0, stream,
                       pred, labels, psum, pcnt, lastg);
    hipLaunchKernelGGL(gce_final, dim3(1), dim3(256), 0, stream,
                       psum, pcnt, lastg, out);
}